// Round 14
// baseline (102.721 us; speedup 1.0000x reference)
//
#include <hip/hip_runtime.h>
#include <hip/hip_fp16.h>

// Segment-mean of gathered embeddings.
// Prep (fused): [0,repack_blocks): repack f32 -> fp16 slice-major, 4 slices
//   of 32 dims (emb2[g][item][32]; 64 B granule per item+slice).
//   [repack_blocks, +sess_blocks): per-session binary-search bounds + STABLE
//   PARTITION of ids by item-half into ids2 (prescaled byte offsets),
//   writing starts[] and mid[].
// Gather: block key (blockIdx&7) = (h<<2)|g -> XCD (h*4+g) touches only
//   slice g x item-half h = 3.2 MB (fully L2-resident, r12-proven), and each
//   session's sublist is scanned ONCE (partition removed r12's 2x predicate
//   scan). Pre-scaled partials; trivial combine kernel.

constexpr int D = 128;
constexpr int IDS_CAP = 4096;     // 16 KB LDS; 32 sessions avg ~1600 ids

typedef float f32x2 __attribute__((ext_vector_type(2)));
typedef float f32x4 __attribute__((ext_vector_type(4)));
typedef unsigned int u32x2 __attribute__((ext_vector_type(2)));

// -------- fused prep ------------------------------------------------------
__global__ __launch_bounds__(256)
void prep_kernel(const float* __restrict__ emb, __half* __restrict__ emb2,
                 const int* __restrict__ seg, const int* __restrict__ ids,
                 int* __restrict__ ids2, int* __restrict__ starts,
                 int* __restrict__ mid,
                 int nitems, int total, int nsess, int repack_blocks,
                 int do_part) {
    if ((int)blockIdx.x < repack_blocks) {
        const int item = blockIdx.x * 4 + (threadIdx.x >> 6);
        if (item >= nitems) return;
        const int lane = threadIdx.x & 63;
        const f32x2 v = __builtin_nontemporal_load(
            reinterpret_cast<const f32x2*>(emb + (size_t)item * D) + lane);
        const __half2 h = __floats2half2_rn(v.x, v.y);
        const int g = lane >> 4;                   // 32-dim slice 0..3
        const int o = lane & 15;                   // half2 slot within slice
        __half2* dst = reinterpret_cast<__half2*>(
            emb2 + (size_t)g * nitems * 32 + (size_t)item * 32);
        dst[o] = h;
    } else {
        const int s = ((int)blockIdx.x - repack_blocks) * 256 + threadIdx.x;
        if (s > nsess) return;
        // starts[s] = lower_bound(seg, s)
        int lo = 0, hi = total;
        while (lo < hi) { const int m = (lo + hi) >> 1;
                          if (seg[m] < s) lo = m + 1; else hi = m; }
        starts[s] = lo;
        if (!do_part || s == nsess) return;
        // e = lower_bound(seg, s+1)
        int lo2 = lo, hi2 = total;
        while (lo2 < hi2) { const int m = (lo2 + hi2) >> 1;
                            if (seg[m] < s + 1) lo2 = m + 1; else hi2 = m; }
        const int e = lo2;
        const int half = nitems >> 1;
        int nlow = 0;
        for (int j = lo; j < e; ++j) nlow += (ids[j] < half) ? 1 : 0;
        mid[s] = lo + nlow;
        int c0 = lo, c1 = lo + nlow;
        for (int j = lo; j < e; ++j) {
            const int id = ids[j];
            if (id < half) ids2[c0++] = id << 6;   // prescaled byte offset
            else           ids2[c1++] = id << 6;
        }
    }
}

// Block = 32 sessions x 8 dl; key = (h<<2)|g. Scans the session's h-sublist
// once; writes pre-scaled partial[h].
__global__ __launch_bounds__(256)
void gather_mean_part(const __half* __restrict__ emb2,
                      const int* __restrict__ ids2,
                      const int* __restrict__ starts,
                      const int* __restrict__ mid,
                      float* __restrict__ partial,   // [2][nsess][128]
                      int nitems, int nsess) {
    __shared__ int lds_off[IDS_CAP];

    const int key  = blockIdx.x & 7;
    const int g    = key & 3;                          // dim-slice
    const int hh   = key >> 2;                         // item half
    const int s0   = (blockIdx.x >> 3) * 32;
    const int sidx = s0 + (threadIdx.x >> 3);
    const int dl   = threadIdx.x & 7;   // dims g*32 + 4*dl .. +3

    const int sEnd  = (s0 + 32 < nsess) ? s0 + 32 : nsess;
    const int base0 = starts[s0];
    const int range = starts[sEnd] - base0;
    const bool use_lds = (range <= IDS_CAP);

    if (use_lds) {
        for (int t = threadIdx.x; t < range; t += 256)
            lds_off[t] = ids2[base0 + t];         // already byte offsets
    }
    __syncthreads();

    if (sidx >= nsess) return;

    const int lo  = starts[sidx];
    const int hix = starts[sidx + 1];
    const int m   = mid[sidx];
    const int b   = hh ? m : lo;
    const int e   = hh ? hix : m;
    const int lenh = e - b;
    const int flen = hix - lo;

    const char* pbase = reinterpret_cast<const char*>(emb2)
                      + (size_t)g * nitems * 64 + dl * 8;

    float a0 = 0.f, a1 = 0.f, a2 = 0.f, a3 = 0.f;

    if (use_lds) {
        const int* offp = lds_off + (b - base0);
        int j = 0;
        for (; j + 8 <= lenh; j += 8) {
            int off[8];
            #pragma unroll
            for (int k = 0; k < 8; ++k) off[k] = offp[j + k];
            u32x2 r[8];
            #pragma unroll
            for (int k = 0; k < 8; ++k)
                r[k] = *reinterpret_cast<const u32x2*>(pbase + (size_t)off[k]);
            #pragma unroll
            for (int k = 0; k < 8; ++k) {
                unsigned lov = r[k].x, hiv = r[k].y;
                const float2 f0 = __half22float2(*reinterpret_cast<const __half2*>(&lov));
                const float2 f1 = __half22float2(*reinterpret_cast<const __half2*>(&hiv));
                a0 += f0.x; a1 += f0.y; a2 += f1.x; a3 += f1.y;
            }
        }
        for (; j < lenh; ++j) {
            const u32x2 r = *reinterpret_cast<const u32x2*>(pbase + (size_t)offp[j]);
            unsigned lov = r.x, hiv = r.y;
            const float2 f0 = __half22float2(*reinterpret_cast<const __half2*>(&lov));
            const float2 f1 = __half22float2(*reinterpret_cast<const __half2*>(&hiv));
            a0 += f0.x; a1 += f0.y; a2 += f1.x; a3 += f1.y;
        }
    } else {                                   // overflow fallback (rare)
        const int* offp = ids2 + b;
        for (int j = 0; j < lenh; ++j) {
            const u32x2 r = *reinterpret_cast<const u32x2*>(pbase + (size_t)offp[j]);
            unsigned lov = r.x, hiv = r.y;
            const float2 f0 = __half22float2(*reinterpret_cast<const __half2*>(&lov));
            const float2 f1 = __half22float2(*reinterpret_cast<const __half2*>(&hiv));
            a0 += f0.x; a1 += f0.y; a2 += f1.x; a3 += f1.y;
        }
    }

    const float inv = (flen > 0) ? 1.0f / (float)flen : 0.0f;
    f32x4 o = {a0 * inv, a1 * inv, a2 * inv, a3 * inv};
    float* dst = partial + (size_t)hh * nsess * D + (size_t)sidx * D
               + g * 32 + dl * 4;
    __builtin_nontemporal_store(o, reinterpret_cast<f32x4*>(dst));
}

// out = pA + pB (both pre-scaled), f32x4 streaming.
__global__ __launch_bounds__(256)
void combine_kernel(const float* __restrict__ partial, float* __restrict__ out,
                    int n4) {
    const int i = blockIdx.x * 256 + threadIdx.x;
    if (i >= n4) return;
    const f32x4 a = __builtin_nontemporal_load(
        reinterpret_cast<const f32x4*>(partial) + i);
    const f32x4 b = __builtin_nontemporal_load(
        reinterpret_cast<const f32x4*>(partial) + n4 + i);
    f32x4 o = {a.x + b.x, a.y + b.y, a.z + b.z, a.w + b.w};
    reinterpret_cast<f32x4*>(out)[i] = o;
}

// ---------------- mid tier (round-11 gather, no item split) ----------------
__global__ __launch_bounds__(256)
void gather_mean_g4(const __half* __restrict__ emb2,
                    const int* __restrict__ ids,
                    const int* __restrict__ starts,
                    float* __restrict__ out,
                    int nitems, int nsess) {
    __shared__ int lds_off[IDS_CAP];

    const int g    = blockIdx.x & 3;
    const int s0   = (blockIdx.x >> 2) * 32;
    const int sidx = s0 + (threadIdx.x >> 3);
    const int dl   = threadIdx.x & 7;

    const int sEnd  = (s0 + 32 < nsess) ? s0 + 32 : nsess;
    const int base0 = starts[s0];
    const int range = starts[sEnd] - base0;
    const bool use_lds = (range <= IDS_CAP);

    if (use_lds) {
        for (int t = threadIdx.x; t < range; t += 256)
            lds_off[t] = ids[base0 + t] << 6;
    }
    __syncthreads();

    if (sidx >= nsess) return;

    const int beg = starts[sidx];
    const int len = starts[sidx + 1] - beg;

    const char* pbase = reinterpret_cast<const char*>(emb2)
                      + (size_t)g * nitems * 64 + dl * 8;

    float a0 = 0.f, a1 = 0.f, a2 = 0.f, a3 = 0.f;

    if (use_lds) {
        const int* offp = lds_off + (beg - base0);
        int j = 0;
        for (; j + 8 <= len; j += 8) {
            int off[8];
            #pragma unroll
            for (int k = 0; k < 8; ++k) off[k] = offp[j + k];
            u32x2 r[8];
            #pragma unroll
            for (int k = 0; k < 8; ++k)
                r[k] = *reinterpret_cast<const u32x2*>(pbase + (size_t)off[k]);
            #pragma unroll
            for (int k = 0; k < 8; ++k) {
                unsigned lov = r[k].x, hiv = r[k].y;
                const float2 f0 = __half22float2(*reinterpret_cast<const __half2*>(&lov));
                const float2 f1 = __half22float2(*reinterpret_cast<const __half2*>(&hiv));
                a0 += f0.x; a1 += f0.y; a2 += f1.x; a3 += f1.y;
            }
        }
        for (; j < len; ++j) {
            const u32x2 r = *reinterpret_cast<const u32x2*>(pbase + (size_t)offp[j]);
            unsigned lov = r.x, hiv = r.y;
            const float2 f0 = __half22float2(*reinterpret_cast<const __half2*>(&lov));
            const float2 f1 = __half22float2(*reinterpret_cast<const __half2*>(&hiv));
            a0 += f0.x; a1 += f0.y; a2 += f1.x; a3 += f1.y;
        }
    } else {
        const int* idp = ids + beg;
        for (int j = 0; j < len; ++j) {
            const u32x2 r = *reinterpret_cast<const u32x2*>(
                pbase + ((size_t)idp[j] << 6));
            unsigned lov = r.x, hiv = r.y;
            const float2 f0 = __half22float2(*reinterpret_cast<const __half2*>(&lov));
            const float2 f1 = __half22float2(*reinterpret_cast<const __half2*>(&hiv));
            a0 += f0.x; a1 += f0.y; a2 += f1.x; a3 += f1.y;
        }
    }

    const float inv = (len > 0) ? 1.0f / (float)len : 0.0f;
    f32x4 o = {a0 * inv, a1 * inv, a2 * inv, a3 * inv};
    *reinterpret_cast<f32x4*>(out + (size_t)sidx * D + g * 32 + dl * 4) = o;
}

// ---------------- last tier (ws tiny): round-2 direct f32 gather -----------
__global__ void find_starts_diff(const int* __restrict__ seg, int total,
                                 int nsess, int* __restrict__ starts) {
    int j = blockIdx.x * blockDim.x + threadIdx.x;
    if (j >= total) return;
    const int cur  = seg[j];
    const int prev = (j == 0) ? -1 : seg[j - 1];
    for (int s = prev + 1; s <= cur; ++s) starts[s] = j;
    if (j == total - 1) {
        for (int s = cur + 1; s <= nsess; ++s) starts[s] = total;
    }
}

__global__ __launch_bounds__(256)
void seg_mean_kernel(const float* __restrict__ emb,
                     const int* __restrict__ ids,
                     const int* __restrict__ starts,
                     float* __restrict__ out, int nsess) {
    const int tid  = threadIdx.x;
    const int s    = blockIdx.x * 4 + (tid >> 6);
    if (s >= nsess) return;
    const int lane = tid & 63;
    const int gq   = lane >> 5;
    const int l32  = lane & 31;

    const int beg = starts[s];
    const int end = starts[s + 1];

    float4 acc = make_float4(0.f, 0.f, 0.f, 0.f);
    for (int j = beg + gq; j < end; j += 2) {
        const int id = ids[j];
        const float4 v = reinterpret_cast<const float4*>(emb + (size_t)id * D)[l32];
        acc.x += v.x; acc.y += v.y; acc.z += v.z; acc.w += v.w;
    }
    acc.x += __shfl_down(acc.x, 32);
    acc.y += __shfl_down(acc.y, 32);
    acc.z += __shfl_down(acc.z, 32);
    acc.w += __shfl_down(acc.w, 32);
    if (lane < 32) {
        const int cnt = end - beg;
        const float inv = (cnt > 0) ? 1.0f / (float)cnt : 0.0f;
        const float4 o = make_float4(acc.x * inv, acc.y * inv,
                                     acc.z * inv, acc.w * inv);
        reinterpret_cast<float4*>(out + (size_t)s * D)[l32] = o;
    }
}

extern "C" void kernel_launch(void* const* d_in, const int* in_sizes, int n_in,
                              void* d_out, int out_size, void* d_ws, size_t ws_size,
                              hipStream_t stream) {
    const float* emb = (const float*)d_in[0];
    const int*   ids = (const int*)d_in[1];
    const int*   seg = (const int*)d_in[2];
    float*       out = (float*)d_out;

    const int total  = in_sizes[1];        // TOTAL_ITEMS
    const int nsess  = out_size / D;       // N_SESSIONS
    const int nitems = in_sizes[0] / D;    // N_ITEMS

    auto pad = [](size_t x) { return (x + 255) & ~(size_t)255; };
    const size_t emb2_pad    = pad((size_t)nitems * D * 2);       // 25.6 MB
    const size_t ids2_pad    = pad((size_t)total * 4);            //  3.3 MB
    const size_t starts_pad  = pad((size_t)(nsess + 1) * 4);
    const size_t mid_pad     = pad((size_t)nsess * 4);
    const size_t partial_sz  = (size_t)2 * nsess * D * 4;         // 16.8 MB
    const size_t need_full   = emb2_pad + ids2_pad + starts_pad + mid_pad + partial_sz;
    const size_t need_mid    = emb2_pad + (size_t)(nsess + 1) * 4;

    const int repack_blocks = (nitems + 3) / 4;
    const int sess_blocks   = (nsess + 1 + 255) / 256;

    if (ws_size >= need_full) {
        char* w = (char*)d_ws;
        __half* emb2    = (__half*)w;                  w += emb2_pad;
        int*    ids2    = (int*)w;                     w += ids2_pad;
        int*    starts  = (int*)w;                     w += starts_pad;
        int*    midp    = (int*)w;                     w += mid_pad;
        float*  partial = (float*)w;

        prep_kernel<<<repack_blocks + sess_blocks, 256, 0, stream>>>(
            emb, emb2, seg, ids, ids2, starts, midp,
            nitems, total, nsess, repack_blocks, 1);

        const int sgroups = (nsess + 31) / 32;
        gather_mean_part<<<sgroups * 8, 256, 0, stream>>>(
            emb2, ids2, starts, midp, partial, nitems, nsess);

        const int n4 = nsess * (D / 4);
        combine_kernel<<<(n4 + 255) / 256, 256, 0, stream>>>(partial, out, n4);
    } else if (ws_size >= need_mid) {
        __half* emb2   = (__half*)d_ws;
        int*    starts = (int*)((char*)d_ws + emb2_pad);

        prep_kernel<<<repack_blocks + sess_blocks, 256, 0, stream>>>(
            emb, emb2, seg, ids, nullptr, starts, nullptr,
            nitems, total, nsess, repack_blocks, 0);

        const int sgroups = (nsess + 31) / 32;
        gather_mean_g4<<<sgroups * 4, 256, 0, stream>>>(emb2, ids, starts,
                                                        out, nitems, nsess);
    } else {
        int* starts = (int*)d_ws;
        const int blocks = (total + 255) / 256;
        find_starts_diff<<<blocks, 256, 0, stream>>>(seg, total, nsess, starts);
        const int sblocks = (nsess + 3) / 4;
        seg_mean_kernel<<<sblocks, 256, 0, stream>>>(emb, ids, starts, out, nsess);
    }
}

// Round 15
// 61.135 us; speedup vs baseline: 1.6802x; 1.6802x over previous
//
#include <hip/hip_runtime.h>
#include <hip/hip_fp16.h>

// Segment-mean of gathered embeddings.
// K1 prep (fused, r13-proven): repack f32 -> fp16 slice-major (4 slices of
//    32 dims, 64 B granule) + item-parallel diff-scan -> starts[].
// K2 part: ONE WAVE PER SESSION ballot-partition of ids by item-half into
//    ids2 (prescaled byte offsets), mid[]. Lows from front, highs from back
//    (bucket order irrelevant for a mean).
// K3 gather (r14-proven): block key (blockIdx&7)=(h<<2)|g -> XCD h*4+g only
//    touches slice g x item-half h = 3.2 MB (L2-resident, r12-proven FETCH),
//    each session's half-sublist scanned ONCE. Pre-scaled partials.
// K4 combine (proven): out = partial[0] + partial[1].

constexpr int D = 128;
constexpr int IDS_CAP = 4096;     // 16 KB LDS; 32 sessions avg ~1600 ids

typedef float f32x2 __attribute__((ext_vector_type(2)));
typedef float f32x4 __attribute__((ext_vector_type(4)));
typedef unsigned int u32x2 __attribute__((ext_vector_type(2)));

// -------- K1: fused repack + diff-scan starts (r13-proven) ----------------
__global__ __launch_bounds__(256)
void prep_kernel(const float* __restrict__ emb, __half* __restrict__ emb2,
                 const int* __restrict__ seg, int* __restrict__ starts,
                 int nitems, int total, int nsess, int repack_blocks) {
    if ((int)blockIdx.x < repack_blocks) {
        const int item = blockIdx.x * 4 + (threadIdx.x >> 6);
        if (item >= nitems) return;
        const int lane = threadIdx.x & 63;
        const f32x2 v = __builtin_nontemporal_load(
            reinterpret_cast<const f32x2*>(emb + (size_t)item * D) + lane);
        const __half2 h = __floats2half2_rn(v.x, v.y);
        const int g = lane >> 4;                   // 32-dim slice 0..3
        const int o = lane & 15;                   // half2 slot within slice
        __half2* dst = reinterpret_cast<__half2*>(
            emb2 + (size_t)g * nitems * 32 + (size_t)item * 32);
        dst[o] = h;
    } else {
        const int j = ((int)blockIdx.x - repack_blocks) * 256 + threadIdx.x;
        if (j >= total) return;
        const int cur  = seg[j];
        const int prev = (j == 0) ? -1 : seg[j - 1];
        for (int s = prev + 1; s <= cur; ++s) starts[s] = j;
        if (j == total - 1) {
            for (int s = cur + 1; s <= nsess; ++s) starts[s] = total;
        }
    }
}

// -------- K2: wave-per-session ballot partition ---------------------------
__global__ __launch_bounds__(256)
void part_kernel(const int* __restrict__ ids, const int* __restrict__ starts,
                 int* __restrict__ ids2, int* __restrict__ mid,
                 int nitems, int nsess) {
    const int s = blockIdx.x * 4 + (threadIdx.x >> 6);
    if (s >= nsess) return;
    const int lane = threadIdx.x & 63;
    const unsigned long long below = (1ull << lane) - 1ull;

    const int beg  = starts[s];
    const int end  = starts[s + 1];
    const int half = nitems >> 1;

    int c0 = beg;          // low bucket fill pointer (front)
    int c1 = end;          // high bucket fill pointer (back, exclusive)
    for (int c = beg; c < end; c += 64) {
        const int j = c + lane;
        const bool valid = (j < end);
        const int id = valid ? ids[j] : 0;
        const bool low  = valid && (id < half);
        const bool high = valid && !low;
        const unsigned long long mlow  = __ballot(low);
        const unsigned long long mhigh = __ballot(high);
        if (low)
            ids2[c0 + __popcll(mlow & below)] = id << 6;       // byte offset
        else if (high)
            ids2[c1 - 1 - __popcll(mhigh & below)] = id << 6;
        c0 += (int)__popcll(mlow);     // wave-uniform
        c1 -= (int)__popcll(mhigh);
    }
    if (lane == 0) mid[s] = c0;        // == c1
}

// -------- K3: gather, half-partitioned (r14-proven logic) -----------------
__global__ __launch_bounds__(256)
void gather_mean_part(const __half* __restrict__ emb2,
                      const int* __restrict__ ids2,
                      const int* __restrict__ starts,
                      const int* __restrict__ mid,
                      float* __restrict__ partial,   // [2][nsess][128]
                      int nitems, int nsess) {
    __shared__ int lds_off[IDS_CAP];

    const int key  = blockIdx.x & 7;
    const int g    = key & 3;                          // dim-slice
    const int hh   = key >> 2;                         // item half
    const int s0   = (blockIdx.x >> 3) * 32;
    const int sidx = s0 + (threadIdx.x >> 3);
    const int dl   = threadIdx.x & 7;   // dims g*32 + 4*dl .. +3

    const int sEnd  = (s0 + 32 < nsess) ? s0 + 32 : nsess;
    const int base0 = starts[s0];
    const int range = starts[sEnd] - base0;
    const bool use_lds = (range <= IDS_CAP);

    if (use_lds) {
        for (int t = threadIdx.x; t < range; t += 256)
            lds_off[t] = ids2[base0 + t];         // already byte offsets
    }
    __syncthreads();

    if (sidx >= nsess) return;

    const int lo  = starts[sidx];
    const int hix = starts[sidx + 1];
    const int m   = mid[sidx];
    const int b   = hh ? m : lo;
    const int e   = hh ? hix : m;
    const int lenh = e - b;
    const int flen = hix - lo;

    const char* pbase = reinterpret_cast<const char*>(emb2)
                      + (size_t)g * nitems * 64 + dl * 8;

    float a0 = 0.f, a1 = 0.f, a2 = 0.f, a3 = 0.f;

    if (use_lds) {
        const int* offp = lds_off + (b - base0);
        int j = 0;
        for (; j + 8 <= lenh; j += 8) {
            int off[8];
            #pragma unroll
            for (int k = 0; k < 8; ++k) off[k] = offp[j + k];
            u32x2 r[8];
            #pragma unroll
            for (int k = 0; k < 8; ++k)
                r[k] = *reinterpret_cast<const u32x2*>(pbase + (size_t)off[k]);
            #pragma unroll
            for (int k = 0; k < 8; ++k) {
                unsigned lov = r[k].x, hiv = r[k].y;
                const float2 f0 = __half22float2(*reinterpret_cast<const __half2*>(&lov));
                const float2 f1 = __half22float2(*reinterpret_cast<const __half2*>(&hiv));
                a0 += f0.x; a1 += f0.y; a2 += f1.x; a3 += f1.y;
            }
        }
        for (; j < lenh; ++j) {
            const u32x2 r = *reinterpret_cast<const u32x2*>(pbase + (size_t)offp[j]);
            unsigned lov = r.x, hiv = r.y;
            const float2 f0 = __half22float2(*reinterpret_cast<const __half2*>(&lov));
            const float2 f1 = __half22float2(*reinterpret_cast<const __half2*>(&hiv));
            a0 += f0.x; a1 += f0.y; a2 += f1.x; a3 += f1.y;
        }
    } else {                                   // overflow fallback (rare)
        const int* offp = ids2 + b;
        for (int j = 0; j < lenh; ++j) {
            const u32x2 r = *reinterpret_cast<const u32x2*>(pbase + (size_t)offp[j]);
            unsigned lov = r.x, hiv = r.y;
            const float2 f0 = __half22float2(*reinterpret_cast<const __half2*>(&lov));
            const float2 f1 = __half22float2(*reinterpret_cast<const __half2*>(&hiv));
            a0 += f0.x; a1 += f0.y; a2 += f1.x; a3 += f1.y;
        }
    }

    const float inv = (flen > 0) ? 1.0f / (float)flen : 0.0f;
    f32x4 o = {a0 * inv, a1 * inv, a2 * inv, a3 * inv};
    float* dst = partial + (size_t)hh * nsess * D + (size_t)sidx * D
               + g * 32 + dl * 4;
    __builtin_nontemporal_store(o, reinterpret_cast<f32x4*>(dst));
}

// -------- K4: out = pA + pB (both pre-scaled) -----------------------------
__global__ __launch_bounds__(256)
void combine_kernel(const float* __restrict__ partial, float* __restrict__ out,
                    int n4) {
    const int i = blockIdx.x * 256 + threadIdx.x;
    if (i >= n4) return;
    const f32x4 a = __builtin_nontemporal_load(
        reinterpret_cast<const f32x4*>(partial) + i);
    const f32x4 b = __builtin_nontemporal_load(
        reinterpret_cast<const f32x4*>(partial) + n4 + i);
    f32x4 o = {a.x + b.x, a.y + b.y, a.z + b.z, a.w + b.w};
    reinterpret_cast<f32x4*>(out)[i] = o;
}

// ---------------- mid tier (round-11 gather, no item split) ----------------
__global__ __launch_bounds__(256)
void gather_mean_g4(const __half* __restrict__ emb2,
                    const int* __restrict__ ids,
                    const int* __restrict__ starts,
                    float* __restrict__ out,
                    int nitems, int nsess) {
    __shared__ int lds_off[IDS_CAP];

    const int g    = blockIdx.x & 3;
    const int s0   = (blockIdx.x >> 2) * 32;
    const int sidx = s0 + (threadIdx.x >> 3);
    const int dl   = threadIdx.x & 7;

    const int sEnd  = (s0 + 32 < nsess) ? s0 + 32 : nsess;
    const int base0 = starts[s0];
    const int range = starts[sEnd] - base0;
    const bool use_lds = (range <= IDS_CAP);

    if (use_lds) {
        for (int t = threadIdx.x; t < range; t += 256)
            lds_off[t] = ids[base0 + t] << 6;
    }
    __syncthreads();

    if (sidx >= nsess) return;

    const int beg = starts[sidx];
    const int len = starts[sidx + 1] - beg;

    const char* pbase = reinterpret_cast<const char*>(emb2)
                      + (size_t)g * nitems * 64 + dl * 8;

    float a0 = 0.f, a1 = 0.f, a2 = 0.f, a3 = 0.f;

    if (use_lds) {
        const int* offp = lds_off + (beg - base0);
        int j = 0;
        for (; j + 8 <= len; j += 8) {
            int off[8];
            #pragma unroll
            for (int k = 0; k < 8; ++k) off[k] = offp[j + k];
            u32x2 r[8];
            #pragma unroll
            for (int k = 0; k < 8; ++k)
                r[k] = *reinterpret_cast<const u32x2*>(pbase + (size_t)off[k]);
            #pragma unroll
            for (int k = 0; k < 8; ++k) {
                unsigned lov = r[k].x, hiv = r[k].y;
                const float2 f0 = __half22float2(*reinterpret_cast<const __half2*>(&lov));
                const float2 f1 = __half22float2(*reinterpret_cast<const __half2*>(&hiv));
                a0 += f0.x; a1 += f0.y; a2 += f1.x; a3 += f1.y;
            }
        }
        for (; j < len; ++j) {
            const u32x2 r = *reinterpret_cast<const u32x2*>(pbase + (size_t)offp[j]);
            unsigned lov = r.x, hiv = r.y;
            const float2 f0 = __half22float2(*reinterpret_cast<const __half2*>(&lov));
            const float2 f1 = __half22float2(*reinterpret_cast<const __half2*>(&hiv));
            a0 += f0.x; a1 += f0.y; a2 += f1.x; a3 += f1.y;
        }
    } else {
        const int* idp = ids + beg;
        for (int j = 0; j < len; ++j) {
            const u32x2 r = *reinterpret_cast<const u32x2*>(
                pbase + ((size_t)idp[j] << 6));
            unsigned lov = r.x, hiv = r.y;
            const float2 f0 = __half22float2(*reinterpret_cast<const __half2*>(&lov));
            const float2 f1 = __half22float2(*reinterpret_cast<const __half2*>(&hiv));
            a0 += f0.x; a1 += f0.y; a2 += f1.x; a3 += f1.y;
        }
    }

    const float inv = (len > 0) ? 1.0f / (float)len : 0.0f;
    f32x4 o = {a0 * inv, a1 * inv, a2 * inv, a3 * inv};
    *reinterpret_cast<f32x4*>(out + (size_t)sidx * D + g * 32 + dl * 4) = o;
}

// ---------------- last tier (ws tiny): round-2 direct f32 gather -----------
__global__ void find_starts_diff(const int* __restrict__ seg, int total,
                                 int nsess, int* __restrict__ starts) {
    int j = blockIdx.x * blockDim.x + threadIdx.x;
    if (j >= total) return;
    const int cur  = seg[j];
    const int prev = (j == 0) ? -1 : seg[j - 1];
    for (int s = prev + 1; s <= cur; ++s) starts[s] = j;
    if (j == total - 1) {
        for (int s = cur + 1; s <= nsess; ++s) starts[s] = total;
    }
}

__global__ __launch_bounds__(256)
void seg_mean_kernel(const float* __restrict__ emb,
                     const int* __restrict__ ids,
                     const int* __restrict__ starts,
                     float* __restrict__ out, int nsess) {
    const int tid  = threadIdx.x;
    const int s    = blockIdx.x * 4 + (tid >> 6);
    if (s >= nsess) return;
    const int lane = tid & 63;
    const int gq   = lane >> 5;
    const int l32  = lane & 31;

    const int beg = starts[s];
    const int end = starts[s + 1];

    float4 acc = make_float4(0.f, 0.f, 0.f, 0.f);
    for (int j = beg + gq; j < end; j += 2) {
        const int id = ids[j];
        const float4 v = reinterpret_cast<const float4*>(emb + (size_t)id * D)[l32];
        acc.x += v.x; acc.y += v.y; acc.z += v.z; acc.w += v.w;
    }
    acc.x += __shfl_down(acc.x, 32);
    acc.y += __shfl_down(acc.y, 32);
    acc.z += __shfl_down(acc.z, 32);
    acc.w += __shfl_down(acc.w, 32);
    if (lane < 32) {
        const int cnt = end - beg;
        const float inv = (cnt > 0) ? 1.0f / (float)cnt : 0.0f;
        const float4 o = make_float4(acc.x * inv, acc.y * inv,
                                     acc.z * inv, acc.w * inv);
        reinterpret_cast<float4*>(out + (size_t)s * D)[l32] = o;
    }
}

extern "C" void kernel_launch(void* const* d_in, const int* in_sizes, int n_in,
                              void* d_out, int out_size, void* d_ws, size_t ws_size,
                              hipStream_t stream) {
    const float* emb = (const float*)d_in[0];
    const int*   ids = (const int*)d_in[1];
    const int*   seg = (const int*)d_in[2];
    float*       out = (float*)d_out;

    const int total  = in_sizes[1];        // TOTAL_ITEMS
    const int nsess  = out_size / D;       // N_SESSIONS
    const int nitems = in_sizes[0] / D;    // N_ITEMS

    auto pad = [](size_t x) { return (x + 255) & ~(size_t)255; };
    const size_t emb2_pad    = pad((size_t)nitems * D * 2);       // 25.6 MB
    const size_t ids2_pad    = pad((size_t)total * 4);            //  3.3 MB
    const size_t starts_pad  = pad((size_t)(nsess + 1) * 4);
    const size_t mid_pad     = pad((size_t)nsess * 4);
    const size_t partial_sz  = (size_t)2 * nsess * D * 4;         // 16.8 MB
    const size_t need_full   = emb2_pad + ids2_pad + starts_pad + mid_pad + partial_sz;
    const size_t need_mid    = emb2_pad + (size_t)(nsess + 1) * 4;

    const int repack_blocks = (nitems + 3) / 4;
    const int starts_blocks = (total + 255) / 256;

    if (ws_size >= need_full) {
        char* w = (char*)d_ws;
        __half* emb2    = (__half*)w;                  w += emb2_pad;
        int*    ids2    = (int*)w;                     w += ids2_pad;
        int*    starts  = (int*)w;                     w += starts_pad;
        int*    midp    = (int*)w;                     w += mid_pad;
        float*  partial = (float*)w;

        prep_kernel<<<repack_blocks + starts_blocks, 256, 0, stream>>>(
            emb, emb2, seg, starts, nitems, total, nsess, repack_blocks);

        part_kernel<<<(nsess + 3) / 4, 256, 0, stream>>>(
            ids, starts, ids2, midp, nitems, nsess);

        const int sgroups = (nsess + 31) / 32;
        gather_mean_part<<<sgroups * 8, 256, 0, stream>>>(
            emb2, ids2, starts, midp, partial, nitems, nsess);

        const int n4 = nsess * (D / 4);
        combine_kernel<<<(n4 + 255) / 256, 256, 0, stream>>>(partial, out, n4);
    } else if (ws_size >= need_mid) {
        __half* emb2   = (__half*)d_ws;
        int*    starts = (int*)((char*)d_ws + emb2_pad);

        prep_kernel<<<repack_blocks + starts_blocks, 256, 0, stream>>>(
            emb, emb2, seg, starts, nitems, total, nsess, repack_blocks);

        const int sgroups = (nsess + 31) / 32;
        gather_mean_g4<<<sgroups * 4, 256, 0, stream>>>(emb2, ids, starts,
                                                        out, nitems, nsess);
    } else {
        int* starts = (int*)d_ws;
        const int blocks = (total + 255) / 256;
        find_starts_diff<<<blocks, 256, 0, stream>>>(seg, total, nsess, starts);
        const int sblocks = (nsess + 3) / 4;
        seg_mean_kernel<<<sblocks, 256, 0, stream>>>(emb, ids, starts, out, nsess);
    }
}

// Round 16
// 54.168 us; speedup vs baseline: 1.8963x; 1.1286x over previous
//
#include <hip/hip_runtime.h>
#include <hip/hip_fp16.h>

// Segment-mean of gathered embeddings.  (Best-measured config: round 13, 54.2 us)
// Prep (fused): starts[] diff-scan + repack f32 -> fp16, 4 slices of 32 dims:
//   emb2[g][item][32] halves; granule per (item,slice) = 64 B (one L2 line).
// Gather: block = 64 sessions x 4 dl, slice g = blockIdx%4 (XCD-affine via
//   round-robin dispatch). Thread loads 16 B (dims g*32+8*dl..+7) per item.
//   ids staged in LDS as prescaled byte offsets; 8-deep unroll.

constexpr int D = 128;
constexpr int IDS_CAP = 6144;     // 24 KB LDS; 64 sessions avg ~3200 ids (+50 sigma)

typedef float f32x2 __attribute__((ext_vector_type(2)));
typedef float f32x4 __attribute__((ext_vector_type(4)));
typedef unsigned int u32x4 __attribute__((ext_vector_type(4)));

// -------- fused prep: blocks [0, repack_blocks) repack, rest diff-scan -----
__global__ __launch_bounds__(256)
void prep_kernel(const float* __restrict__ emb, __half* __restrict__ emb2,
                 const int* __restrict__ seg, int* __restrict__ starts,
                 int nitems, int total, int nsess, int repack_blocks) {
    if ((int)blockIdx.x < repack_blocks) {
        const int item = blockIdx.x * 4 + (threadIdx.x >> 6);
        if (item >= nitems) return;
        const int lane = threadIdx.x & 63;
        const f32x2 v = __builtin_nontemporal_load(
            reinterpret_cast<const f32x2*>(emb + (size_t)item * D) + lane);
        const __half2 h = __floats2half2_rn(v.x, v.y);
        const int g = lane >> 4;                   // 32-dim slice 0..3
        const int o = lane & 15;                   // half2 slot within slice
        __half2* dst = reinterpret_cast<__half2*>(
            emb2 + (size_t)g * nitems * 32 + (size_t)item * 32);
        dst[o] = h;
    } else {
        const int j = ((int)blockIdx.x - repack_blocks) * 256 + threadIdx.x;
        if (j >= total) return;
        const int cur  = seg[j];
        const int prev = (j == 0) ? -1 : seg[j - 1];
        for (int s = prev + 1; s <= cur; ++s) starts[s] = j;
        if (j == total - 1) {
            for (int s = cur + 1; s <= nsess; ++s) starts[s] = total;
        }
    }
}

// Block = 64 sessions x 4 dl, slice g = blockIdx%4. 16 B loads per item.
__global__ __launch_bounds__(256)
void gather_mean_w16(const __half* __restrict__ emb2,
                     const int* __restrict__ ids,
                     const int* __restrict__ starts,
                     float* __restrict__ out,
                     int nitems, int nsess) {
    __shared__ int lds_off[IDS_CAP];

    const int g    = blockIdx.x & 3;                          // XCD-stable slice
    const int s0   = (blockIdx.x >> 2) * 64;
    const int sidx = s0 + (threadIdx.x >> 2);
    const int dl   = threadIdx.x & 3;   // dims g*32 + 8*dl .. +7

    const int sEnd  = (s0 + 64 < nsess) ? s0 + 64 : nsess;
    const int base0 = starts[s0];
    const int range = starts[sEnd] - base0;
    const bool use_lds = (range <= IDS_CAP);

    if (use_lds) {
        for (int t = threadIdx.x; t < range; t += 256)
            lds_off[t] = ids[base0 + t] << 6;     // prescaled byte offset
    }
    __syncthreads();

    if (sidx >= nsess) return;

    const int beg = starts[sidx];
    const int len = starts[sidx + 1] - beg;

    const char* pbase = reinterpret_cast<const char*>(emb2)
                      + (size_t)g * nitems * 64 + dl * 16;

    float a0 = 0.f, a1 = 0.f, a2 = 0.f, a3 = 0.f;
    float a4 = 0.f, a5 = 0.f, a6 = 0.f, a7 = 0.f;

    if (use_lds) {
        const int* offp = lds_off + (beg - base0);
        int j = 0;
        for (; j + 8 <= len; j += 8) {
            int off[8];
            #pragma unroll
            for (int k = 0; k < 8; ++k) off[k] = offp[j + k];
            u32x4 r[8];
            #pragma unroll
            for (int k = 0; k < 8; ++k)
                r[k] = *reinterpret_cast<const u32x4*>(pbase + (size_t)off[k]);
            #pragma unroll
            for (int k = 0; k < 8; ++k) {
                unsigned w0 = r[k].x, w1 = r[k].y, w2 = r[k].z, w3 = r[k].w;
                const float2 f0 = __half22float2(*reinterpret_cast<const __half2*>(&w0));
                const float2 f1 = __half22float2(*reinterpret_cast<const __half2*>(&w1));
                const float2 f2 = __half22float2(*reinterpret_cast<const __half2*>(&w2));
                const float2 f3 = __half22float2(*reinterpret_cast<const __half2*>(&w3));
                a0 += f0.x; a1 += f0.y; a2 += f1.x; a3 += f1.y;
                a4 += f2.x; a5 += f2.y; a6 += f3.x; a7 += f3.y;
            }
        }
        for (; j < len; ++j) {
            const u32x4 r = *reinterpret_cast<const u32x4*>(pbase + (size_t)offp[j]);
            unsigned w0 = r.x, w1 = r.y, w2 = r.z, w3 = r.w;
            const float2 f0 = __half22float2(*reinterpret_cast<const __half2*>(&w0));
            const float2 f1 = __half22float2(*reinterpret_cast<const __half2*>(&w1));
            const float2 f2 = __half22float2(*reinterpret_cast<const __half2*>(&w2));
            const float2 f3 = __half22float2(*reinterpret_cast<const __half2*>(&w3));
            a0 += f0.x; a1 += f0.y; a2 += f1.x; a3 += f1.y;
            a4 += f2.x; a5 += f2.y; a6 += f3.x; a7 += f3.y;
        }
    } else {                                   // overflow fallback (rare)
        const int* idp = ids + beg;
        for (int j = 0; j < len; ++j) {
            const u32x4 r = *reinterpret_cast<const u32x4*>(
                pbase + ((size_t)idp[j] << 6));
            unsigned w0 = r.x, w1 = r.y, w2 = r.z, w3 = r.w;
            const float2 f0 = __half22float2(*reinterpret_cast<const __half2*>(&w0));
            const float2 f1 = __half22float2(*reinterpret_cast<const __half2*>(&w1));
            const float2 f2 = __half22float2(*reinterpret_cast<const __half2*>(&w2));
            const float2 f3 = __half22float2(*reinterpret_cast<const __half2*>(&w3));
            a0 += f0.x; a1 += f0.y; a2 += f1.x; a3 += f1.y;
            a4 += f2.x; a5 += f2.y; a6 += f3.x; a7 += f3.y;
        }
    }

    const float inv = (len > 0) ? 1.0f / (float)len : 0.0f;
    float* dst = out + (size_t)sidx * D + g * 32 + dl * 8;
    f32x4 o0 = {a0 * inv, a1 * inv, a2 * inv, a3 * inv};
    f32x4 o1 = {a4 * inv, a5 * inv, a6 * inv, a7 * inv};
    reinterpret_cast<f32x4*>(dst)[0] = o0;
    reinterpret_cast<f32x4*>(dst)[1] = o1;
}

// ---------------- last tier (ws tiny): round-2 direct f32 gather -----------
__global__ void find_starts_diff(const int* __restrict__ seg, int total,
                                 int nsess, int* __restrict__ starts) {
    int j = blockIdx.x * blockDim.x + threadIdx.x;
    if (j >= total) return;
    const int cur  = seg[j];
    const int prev = (j == 0) ? -1 : seg[j - 1];
    for (int s = prev + 1; s <= cur; ++s) starts[s] = j;
    if (j == total - 1) {
        for (int s = cur + 1; s <= nsess; ++s) starts[s] = total;
    }
}

__global__ __launch_bounds__(256)
void seg_mean_kernel(const float* __restrict__ emb,
                     const int* __restrict__ ids,
                     const int* __restrict__ starts,
                     float* __restrict__ out, int nsess) {
    const int tid  = threadIdx.x;
    const int s    = blockIdx.x * 4 + (tid >> 6);
    if (s >= nsess) return;
    const int lane = tid & 63;
    const int gq   = lane >> 5;
    const int l32  = lane & 31;

    const int beg = starts[s];
    const int end = starts[s + 1];

    float4 acc = make_float4(0.f, 0.f, 0.f, 0.f);
    for (int j = beg + gq; j < end; j += 2) {
        const int id = ids[j];
        const float4 v = reinterpret_cast<const float4*>(emb + (size_t)id * D)[l32];
        acc.x += v.x; acc.y += v.y; acc.z += v.z; acc.w += v.w;
    }
    acc.x += __shfl_down(acc.x, 32);
    acc.y += __shfl_down(acc.y, 32);
    acc.z += __shfl_down(acc.z, 32);
    acc.w += __shfl_down(acc.w, 32);
    if (lane < 32) {
        const int cnt = end - beg;
        const float inv = (cnt > 0) ? 1.0f / (float)cnt : 0.0f;
        const float4 o = make_float4(acc.x * inv, acc.y * inv,
                                     acc.z * inv, acc.w * inv);
        reinterpret_cast<float4*>(out + (size_t)s * D)[l32] = o;
    }
}

extern "C" void kernel_launch(void* const* d_in, const int* in_sizes, int n_in,
                              void* d_out, int out_size, void* d_ws, size_t ws_size,
                              hipStream_t stream) {
    const float* emb = (const float*)d_in[0];
    const int*   ids = (const int*)d_in[1];
    const int*   seg = (const int*)d_in[2];
    float*       out = (float*)d_out;

    const int total  = in_sizes[1];        // TOTAL_ITEMS
    const int nsess  = out_size / D;       // N_SESSIONS
    const int nitems = in_sizes[0] / D;    // N_ITEMS

    const size_t emb2_bytes = (size_t)nitems * D * 2;            // 25.6 MB
    const size_t emb2_pad   = (emb2_bytes + 255) & ~(size_t)255;
    const size_t need       = emb2_pad + (size_t)(nsess + 1) * 4;

    if (ws_size >= need) {
        __half* emb2   = (__half*)d_ws;
        int*    starts = (int*)((char*)d_ws + emb2_pad);

        const int repack_blocks = (nitems + 3) / 4;
        const int starts_blocks = (total + 255) / 256;
        prep_kernel<<<repack_blocks + starts_blocks, 256, 0, stream>>>(
            emb, emb2, seg, starts, nitems, total, nsess, repack_blocks);

        const int sgroups = (nsess + 63) / 64;
        gather_mean_w16<<<sgroups * 4, 256, 0, stream>>>(emb2, ids, starts,
                                                         out, nitems, nsess);
    } else {
        int* starts = (int*)d_ws;
        const int blocks = (total + 255) / 256;
        find_starts_diff<<<blocks, 256, 0, stream>>>(seg, total, nsess, starts);
        const int sblocks = (nsess + 3) / 4;
        seg_mean_kernel<<<sblocks, 256, 0, stream>>>(emb, ids, starts, out, nsess);
    }
}